// Round 14
// baseline (1054.990 us; speedup 1.0000x reference)
//
#include <hip/hip_runtime.h>

#define NN 100000
#define EE 640000
#define GG 256
#define LL 3
#define HH 128

constexpr int BM = 64;   // rows per block (node gemms)

typedef _Float16 f16;
typedef f16 f16x8 __attribute__((ext_vector_type(8)));
typedef f16 f16x4 __attribute__((ext_vector_type(4)));
typedef f16 f16x2 __attribute__((ext_vector_type(2)));
typedef float f32x4 __attribute__((ext_vector_type(4)));

// padded row stride (halfs) for transposed weight / activation tiles.
// 136 halfs = 272 B = 68 words; 68 % 32 = 4 -> fragment rows land 4 banks
// apart; a wave's b128 fragment read hits the 8-words/bank optimum.
#define TSTR 136

// async global->LDS, 16 B per lane (gfx950). Dest must be linear in lane
// order: HW uses wave-uniform base + lane*16 (m104).
__device__ __forceinline__ void gload_lds16(const void* g, void* l) {
  __builtin_amdgcn_global_load_lds(
      (const __attribute__((address_space(1))) void*)g,
      (__attribute__((address_space(3))) void*)l, 16, 0, 0);
}

// ---------------------------------------------------------------------------
// Weight prep: transpose + fp16-convert + zero-pad ALL weights once into a
// 22-buffer arena of [128 n][TSTR k] halfs (single launch):
//   0:      We0^T          (K=16, msg encoder; k>=16 zero -> K=32 pad works)
//   1..2:   We[l]^T        l=0,1 (msg chain layers)
//   3..5:   WMe[l]^T       = (WM[l] + 2*H*H)^T, l=0..2 (msg projection)
//   6:      Wn0^T          (K=64, node encoder)
//   7..9:   WM1[l]^T       (A projection, dst), l=0..2
//   10..12: WM2[l]^T       (B projection, src)
//   13..15: Wn[l]^T
//   16..21: WU[l]^T        chunks: 16+2l = rows 0..127 (h part),
//                          17+2l = rows 128..255 (agg part)
// ---------------------------------------------------------------------------
__global__ void prep_w(const float* __restrict__ We0,
                       const float* __restrict__ We,
                       const float* __restrict__ WM,
                       const float* __restrict__ Wn0,
                       const float* __restrict__ Wn,
                       const float* __restrict__ WU, f16* __restrict__ out) {
  const int buf = blockIdx.x >> 3;
  const int rowg = blockIdx.x & 7;  // 16 n-rows per block
  const float* src;
  int K;
  if (buf == 0) {
    src = We0; K = 16;
  } else if (buf <= 2) {
    src = We + (size_t)(buf - 1) * HH * HH; K = HH;
  } else if (buf <= 5) {
    src = WM + (size_t)(buf - 3) * 3 * HH * HH + 2 * HH * HH; K = HH;
  } else if (buf == 6) {
    src = Wn0; K = 64;
  } else if (buf <= 9) {
    src = WM + (size_t)(buf - 7) * 3 * HH * HH; K = HH;
  } else if (buf <= 12) {
    src = WM + (size_t)(buf - 10) * 3 * HH * HH + HH * HH; K = HH;
  } else if (buf <= 15) {
    src = Wn + (size_t)(buf - 13) * HH * HH; K = HH;
  } else {
    const int t = buf - 16;
    src = WU + (size_t)(t >> 1) * 2 * HH * HH + (size_t)(t & 1) * HH * HH;
    K = HH;
  }
  f16* dst = out + (size_t)buf * HH * TSTR;
  for (int idx = threadIdx.x; idx < 16 * TSTR; idx += 256) {
    const int n = rowg * 16 + idx / TSTR;
    const int k = idx % TSTR;
    const float v = (k < K) ? src[(size_t)k * HH + n] : 0.f;
    dst[(size_t)n * TSTR + k] = (f16)v;
  }
}

// ---------------------------------------------------------------------------
// Fused node-path kernels via mfma_f32_16x16x32_f16 (r13-verified).
// 64-row x 128-col tile, 4 waves; fragment layouts (measured m89/m91):
//   A[m][k]: m=lane&15, k=8*(lane>>4)+j   B[k][n]: n=lane&15, same k
//   D[m][n]: n=lane&15, m=4*(lane>>4)+reg
// LDS: Xs [64][TSTR] f16 | Wt [128][TSTR] f16 (V f32 [64][132] aliases Wt).
// fused_enc:         h = relu(x@Wn0+b);   A = h@WM1(0); B = h@WM2(0)
// fused_upd<HAS_AB>: h' = relu([h,agg/cnt]@WU+bU); h''= relu(h'@Wn+bn);
//   HAS_AB: A = h''@WM1(l+1); B = h''@WM2(l+1)
//   else (last layer): pool h'' directly from LDS into gsum (r13->r14:
//   removes the h16 store + pool_accum re-read + launch)
// ---------------------------------------------------------------------------
struct GemmCtx {
  f16* Xs; f16* Wt; float* V;
  int tid, lane, wv, l15, q, m0;
};

__device__ __forceinline__ void ctx_init(GemmCtx& c, char* smem) {
  c.Xs = (f16*)smem;
  c.Wt = (f16*)(smem + 17408);
  c.V = (float*)(smem + 17408);
  c.tid = threadIdx.x;
  c.lane = c.tid & 63;
  c.wv = c.tid >> 6;
  c.l15 = c.lane & 15;
  c.q = c.lane >> 4;
  c.m0 = blockIdx.x * 64;
}

__device__ __forceinline__ void c_stageW(GemmCtx& c, const f16* Wg) {
  const char* g = (const char*)Wg;
  char* l = (char*)c.Wt;
#pragma unroll
  for (int i = 0; i < 8; ++i)
    gload_lds16(g + c.tid * 16 + i * 4096, l + c.tid * 16 + i * 4096);
  if (c.tid < 128) gload_lds16(g + c.tid * 16 + 32768, l + c.tid * 16 + 32768);
}

__device__ __forceinline__ void c_stageXf32(GemmCtx& c, const float* Xp,
                                            int stride, int KC, bool scale,
                                            const float* inv, int M) {
  const int npr = KC >> 2;
  for (int i = c.tid; i < 64 * npr; i += 256) {
    const int row = i / npr;
    const int c4 = (i - row * npr) << 2;
    float4 v = make_float4(0.f, 0.f, 0.f, 0.f);
    if (c.m0 + row < M) {
      v = *(const float4*)(Xp + (size_t)(c.m0 + row) * stride + c4);
      if (scale) {
        const float s = inv[c.m0 + row];
        v.x *= s; v.y *= s; v.z *= s; v.w *= s;
      }
    }
    f16x4 hv;
    hv[0] = (f16)v.x; hv[1] = (f16)v.y; hv[2] = (f16)v.z; hv[3] = (f16)v.w;
    *(f16x4*)&c.Xs[(size_t)row * TSTR + c4] = hv;
  }
}

__device__ __forceinline__ void c_stageX16(GemmCtx& c, const f16* Xp, int M) {
  for (int i = c.tid; i < 1024; i += 256) {
    const int row = i >> 4;
    const int c8 = (i & 15) << 3;
    f16x8 v = {};
    if (c.m0 + row < M) v = *(const f16x8*)(Xp + (size_t)(c.m0 + row) * HH + c8);
    *(f16x8*)&c.Xs[(size_t)row * TSTR + c8] = v;
  }
}

__device__ __forceinline__ void c_mfmaN(GemmCtx& c, f32x4 (&ac)[4][2],
                                        int nk) {
  for (int kk = 0; kk < nk; ++kk) {
    f16x8 a[4], b[2];
#pragma unroll
    for (int mi = 0; mi < 4; ++mi)
      a[mi] = *(const f16x8*)&c.Xs[(size_t)(mi * 16 + c.l15) * TSTR + kk * 32 +
                                   c.q * 8];
#pragma unroll
    for (int ni = 0; ni < 2; ++ni)
      b[ni] = *(const f16x8*)&c.Wt[(size_t)((c.wv * 2 + ni) * 16 + c.l15) *
                                       TSTR +
                                   kk * 32 + c.q * 8];
#pragma unroll
    for (int mi = 0; mi < 4; ++mi)
#pragma unroll
      for (int ni = 0; ni < 2; ++ni)
        ac[mi][ni] = __builtin_amdgcn_mfma_f32_16x16x32_f16(a[mi], b[ni],
                                                            ac[mi][ni], 0, 0,
                                                            0);
  }
}

__device__ __forceinline__ void c_zero(f32x4 (&ac)[4][2]) {
#pragma unroll
  for (int mi = 0; mi < 4; ++mi)
#pragma unroll
    for (int ni = 0; ni < 2; ++ni) {
      f32x4 z = {};
      ac[mi][ni] = z;
    }
}

// bias + relu -> f16 into Xs (activation chaining; D-layout indexed)
__device__ __forceinline__ void c_reluXs(GemmCtx& c, f32x4 (&ac)[4][2],
                                         const float* bias) {
  const float bv0 = bias[c.wv * 32 + c.l15];
  const float bv1 = bias[c.wv * 32 + 16 + c.l15];
#pragma unroll
  for (int mi = 0; mi < 4; ++mi)
#pragma unroll
    for (int ni = 0; ni < 2; ++ni) {
      const float bb = ni ? bv1 : bv0;
#pragma unroll
      for (int rr = 0; rr < 4; ++rr) {
        float v = ac[mi][ni][rr] + bb;
        v = v > 0.f ? v : 0.f;
        c.Xs[(size_t)(mi * 16 + c.q * 4 + rr) * TSTR + c.wv * 32 + ni * 16 +
             c.l15] = (f16)v;
      }
    }
}

__device__ __forceinline__ void c_dumpV(GemmCtx& c, f32x4 (&ac)[4][2]) {
#pragma unroll
  for (int mi = 0; mi < 4; ++mi)
#pragma unroll
    for (int ni = 0; ni < 2; ++ni)
#pragma unroll
      for (int rr = 0; rr < 4; ++rr)
        c.V[(size_t)(mi * 16 + c.q * 4 + rr) * 132 + c.wv * 32 + ni * 16 +
            c.l15] = ac[mi][ni][rr];
}

__device__ __forceinline__ void c_storeV16(GemmCtx& c, f16* op, int M) {
  const int tm = (c.tid >> 4) << 2;
  const int tn = (c.tid & 15) << 3;
#pragma unroll
  for (int i = 0; i < 4; ++i) {
    const int r = c.m0 + tm + i;
    if (r >= M) continue;
    const float* vp = &c.V[(size_t)(tm + i) * 132 + tn];
    f16x8 hv;
#pragma unroll
    for (int j = 0; j < 8; ++j) hv[j] = (f16)vp[j];
    *(f16x8*)(op + (size_t)r * HH + tn) = hv;
  }
}

// store Xs (f16 activations) -> global, coalesced f16x8 per thread
__device__ __forceinline__ void c_storeXs16(GemmCtx& c, f16* op, int M) {
  const int tm = (c.tid >> 4) << 2;
  const int tn = (c.tid & 15) << 3;
#pragma unroll
  for (int i = 0; i < 4; ++i) {
    const int r = c.m0 + tm + i;
    if (r >= M) continue;
    *(f16x8*)(op + (size_t)r * HH + tn) =
        *(const f16x8*)&c.Xs[(size_t)(tm + i) * TSTR + tn];
  }
}

// A/B projection pair from h'' already resident in Xs (WA staged by caller).
__device__ __forceinline__ void c_projAB(GemmCtx& c, f32x4 (&ac)[4][2],
                                         const f16* WA, const f16* WBp,
                                         f16* A16, f16* B16, int M) {
  c_zero(ac);
  c_mfmaN(c, ac, 4);             // A = h'' @ WA
  __syncthreads();               // Wt reads done; V may alias
  c_dumpV(c, ac);
  __syncthreads();               // V writes visible
  c_storeV16(c, A16, M);
  __syncthreads();               // V reads done -> Wt reusable
  c_stageW(c, WBp);
  __syncthreads();               // drains WB stage
  c_zero(ac);
  c_mfmaN(c, ac, 4);             // B = h'' @ WB
  __syncthreads();
  c_dumpV(c, ac);
  __syncthreads();
  c_storeV16(c, B16, M);
}

// encoder + A/B(0):  h = relu(x@Wn0+bn0) -> h16; A=h@WA; B=h@WB
__global__ __launch_bounds__(256) void fused_enc(
    const float* __restrict__ x, const f16* __restrict__ Wn0T,
    const float* __restrict__ bn0, f16* __restrict__ h16,
    const f16* __restrict__ WA, const f16* __restrict__ WBp,
    f16* __restrict__ A16, f16* __restrict__ B16, int M) {
  __shared__ __align__(16) char smem[17408 + 34816];
  GemmCtx c; ctx_init(c, smem);
  f32x4 acc[4][2];
  c_zero(acc);
  c_stageW(c, Wn0T);
  c_stageXf32(c, x, 64, 64, false, nullptr, M);
  __syncthreads();
  c_mfmaN(c, acc, 2);            // K=64
  __syncthreads();               // Xs/Wt reads done
  c_reluXs(c, acc, bn0);         // h -> Xs
  c_stageW(c, WA);               // overlaps
  __syncthreads();               // Xs visible + WA staged
  c_storeXs16(c, h16, M);
  c_projAB(c, acc, WA, WBp, A16, B16, M);
}

// per-layer fused: update + node-linear, then A/B (l<2) or pool (last layer)
template <int HAS_AB>
__global__ __launch_bounds__(256) void fused_upd(
    const f16* __restrict__ h, const f16* __restrict__ WU01,
    const float* __restrict__ bU, const float* __restrict__ agg,
    const float* __restrict__ invc, const f16* __restrict__ WnT,
    const float* __restrict__ bn, const f16* __restrict__ WA,
    const f16* __restrict__ WBp, f16* __restrict__ hout,
    f16* __restrict__ A16, f16* __restrict__ B16,
    const int* __restrict__ batch, float* __restrict__ gsum, int M) {
  __shared__ __align__(16) char smem[17408 + 34816];
  __shared__ int bat[64];
  GemmCtx c; ctx_init(c, smem);
  if (!HAS_AB && c.tid < 64 && c.m0 + c.tid < M)
    bat[c.tid] = batch[c.m0 + c.tid];
  f32x4 acc[4][2];
  c_zero(acc);
  // update chunk 0: h @ WU0
  c_stageW(c, WU01);
  c_stageX16(c, h, M);
  __syncthreads();
  c_mfmaN(c, acc, 4);
  __syncthreads();               // Xs/Wt reads done
  // update chunk 1: (agg*inv) @ WU1
  c_stageW(c, WU01 + (size_t)HH * TSTR);
  c_stageXf32(c, agg, HH, 128, true, invc, M);
  __syncthreads();
  c_mfmaN(c, acc, 4);
  __syncthreads();
  c_reluXs(c, acc, bU);          // h' -> Xs
  c_stageW(c, WnT);              // overlaps (Wt reads retired)
  __syncthreads();
  c_zero(acc);
  c_mfmaN(c, acc, 4);            // h' @ Wn
  __syncthreads();
  c_reluXs(c, acc, bn);          // h'' -> Xs
  if (HAS_AB) c_stageW(c, WA);   // overlaps
  __syncthreads();               // Xs(h'') visible (+WA staged)
  if (HAS_AB) {
    c_storeXs16(c, hout, M);
    c_projAB(c, acc, WA, WBp, A16, B16, M);
  } else {
    // pool h'' (f16-rounded, identical numerics to the old h16 round-trip)
    const int col = c.tid & 127;
    const int rg = c.tid >> 7;   // wave-uniform strip 0/1 (rows rg*32..+31)
    const int lo = rg * 32;
    const int hi = min(lo + 32, M - c.m0);
    if (lo < hi) {
      float a2 = 0.f;
      int cur = bat[lo];
      for (int r = lo; r < hi; ++r) {
        const int b = bat[r];
        if (b != cur) {
          atomicAdd(&gsum[(size_t)cur * HH + col], a2);
          a2 = 0.f;
          cur = b;
        }
        a2 += (float)c.Xs[(size_t)r * TSTR + col];
      }
      atomicAdd(&gsum[(size_t)cur * HH + col], a2);
    }
  }
}

// ---------------------------------------------------------------------------
// Fused message kernel via MFMA fp16 (fp32 accumulate), edges sorted by dst.
//   t = relu(ea@We0+be0); CHAIN x (t = relu(t@We_s+be_s)); P = t@WMe
//   v = relu(P + A[dst] + B[src] + bM) -> V16 f16 LDS -> segmented run
//   reduction into agg (boundary atomics + interior stores, r4-verified).
//
// r13->r14 re-tile: the LDS read port is the binding pipe (192 b128
// wave-reads ~2300cy vs ~310cy MFMA per block-phase). Waves now own 64x64
// output tiles (4 waves, 256 thr): 8 reads feed 16 MFMA per wave-kk ->
// 128 wave-reads per block-phase (-33%). acc[4][4] (64 VGPR). Same phase/
// barrier/staging skeleton as the r10-verified kernel.
// Epilogue V16 = f16 [128][TSTR] aliasing Tc (r11-verified layout: halves
// the bank-conflict counter and epilogue LDS bytes; absmax unchanged).
// ---------------------------------------------------------------------------
template <int CHAIN>
__global__ __launch_bounds__(256) void msg_k(
    const float* __restrict__ ea, const f16* __restrict__ W0T,
    const float* __restrict__ be0, const f16* __restrict__ WeT,
    const float* __restrict__ beL, const f16* __restrict__ WMeT,
    const float* __restrict__ bMl, const f16* __restrict__ A,
    const f16* __restrict__ B, const int* __restrict__ sIdx,
    const int* __restrict__ sSrc, const int* __restrict__ sDst,
    float* __restrict__ agg) {
  // LDS: Tc [128][TSTR] f16 (34816 B) | Wc [128][TSTR] f16 (34816 B) |
  // dstS int[128]. V16 f16 [128][TSTR] aliases Tc after the projection.
  __shared__ __align__(16) char smem[34816 + 34816 + 512];
  f16* Tc = (f16*)smem;
  f16* Wc = (f16*)(smem + 34816);
  f16* V16 = (f16*)smem;  // aliases Tc
  int* dstS = (int*)(smem + 69632);

  const int tid = threadIdx.x;
  const int lane = tid & 63;
  const int wv = tid >> 6;        // wave 0..3
  const int eh = (wv >> 1) * 64;  // edge-half offset (0/64)
  const int ch = wv & 1;          // col-half (64 cols)
  const int l15 = lane & 15;
  const int q = lane >> 4;        // 0..3
  const int r0 = blockIdx.x * 128;  // EE % 128 == 0

  auto wptr = [&](int p) -> const f16* {
    if (p == 0) return W0T;
    if (p <= CHAIN) return WeT + (size_t)(p - 1) * HH * TSTR;
    return WMeT;
  };

  // async weight stage: 34816 B via global_load_lds width-16 (256 thr)
  auto stage_w = [&](const f16* Wg) {
    const char* g = (const char*)Wg;
    char* l = (char*)Wc;
#pragma unroll
    for (int i = 0; i < 8; ++i)
      gload_lds16(g + tid * 16 + i * 4096, l + tid * 16 + i * 4096);
    if (tid < 128) gload_lds16(g + tid * 16 + 32768, l + tid * 16 + 32768);
  };

  // ---- prologue: issue W0 async; stage ea tile as fp16 into Tc ----
  stage_w(wptr(0));
  {
    const int xr = tid >> 1;        // edge 0..127
    const int hf = (tid & 1) << 3;  // col 0 or 8
    const int e = sIdx[r0 + xr];
    const float4 v0 = *(const float4*)(ea + (size_t)e * 16 + hf);
    const float4 v1 = *(const float4*)(ea + (size_t)e * 16 + hf + 4);
    f16x8 hv;
    hv[0] = (f16)v0.x; hv[1] = (f16)v0.y; hv[2] = (f16)v0.z; hv[3] = (f16)v0.w;
    hv[4] = (f16)v1.x; hv[5] = (f16)v1.y; hv[6] = (f16)v1.z; hv[7] = (f16)v1.w;
    *(f16x8*)&Tc[(size_t)xr * TSTR + hf] = hv;
    f16x8 z = {};
    *(f16x8*)&Tc[(size_t)xr * TSTR + 16 + hf] = z;  // K pad 16->32
    if (tid < 128) dstS[tid] = sDst[r0 + tid];
  }

  f32x4 acc[4][4];

  auto zero_acc = [&]() {
#pragma unroll
    for (int mi = 0; mi < 4; ++mi)
#pragma unroll
      for (int ni = 0; ni < 4; ++ni) {
        f32x4 z = {};
        acc[mi][ni] = z;
      }
  };

  auto mfma_steps = [&](int nk) {  // nk K=32 steps; 8 reads -> 16 MFMA
    for (int kk = 0; kk < nk; ++kk) {
      f16x8 a[4], b[4];
#pragma unroll
      for (int mi = 0; mi < 4; ++mi)
        a[mi] = *(const f16x8*)&Tc[(size_t)(eh + mi * 16 + l15) * TSTR +
                                   kk * 32 + q * 8];
#pragma unroll
      for (int ni = 0; ni < 4; ++ni)
        b[ni] = *(const f16x8*)&Wc[(size_t)((ch * 4 + ni) * 16 + l15) * TSTR +
                                   kk * 32 + q * 8];
#pragma unroll
      for (int mi = 0; mi < 4; ++mi)
#pragma unroll
        for (int ni = 0; ni < 4; ++ni)
          acc[mi][ni] = __builtin_amdgcn_mfma_f32_16x16x32_f16(
              a[mi], b[ni], acc[mi][ni], 0, 0, 0);
    }
  };

  // bias + relu + fp16 -> write back into Tc (caller brackets with barriers)
  auto relu_body = [&](const float* bias) {
#pragma unroll
    for (int mi = 0; mi < 4; ++mi)
#pragma unroll
      for (int ni = 0; ni < 4; ++ni) {
        const float bb = bias[ch * 64 + ni * 16 + l15];
#pragma unroll
        for (int rr = 0; rr < 4; ++rr) {
          float v = acc[mi][ni][rr] + bb;
          v = v > 0.f ? v : 0.f;
          Tc[(size_t)(eh + mi * 16 + q * 4 + rr) * TSTR + ch * 64 + ni * 16 +
             l15] = (f16)v;
        }
      }
  };

  // ---- phase 0 (encoder): t = relu(ea @ We0 + be0), K=32 zero-padded ----
  zero_acc();
  __syncthreads();               // drains W0 gload + ea stores
  mfma_steps(1);
  __syncthreads();               // Wc reads done
  stage_w(wptr(1));              // async next-phase weights
  relu_body(be0);                // overlaps the loads
  __syncthreads();               // drains; Tc + Wc ready

  // ---- chain: t = relu(t @ We_s + be_s), K=128 ----
#pragma unroll
  for (int s = 0; s < CHAIN; ++s) {
    zero_acc();
    mfma_steps(4);
    __syncthreads();             // Wc/Tc reads done
    stage_w(wptr(s + 2));        // s+2 <= CHAIN+1 = projection
    relu_body(beL + (size_t)s * HH);
    __syncthreads();
  }

  // ---- projection: P = t @ WMe, K=128 ----
  zero_acc();
  mfma_steps(4);
  __syncthreads();  // Tc/Wc reads done; no gloads outstanding; V16 aliases Tc

  // dump P fragments to V16 f16 [128][TSTR] (same indexing as relu_body)
#pragma unroll
  for (int mi = 0; mi < 4; ++mi)
#pragma unroll
    for (int ni = 0; ni < 4; ++ni)
#pragma unroll
      for (int rr = 0; rr < 4; ++rr)
        V16[(size_t)(eh + mi * 16 + q * 4 + rr) * TSTR + ch * 64 + ni * 16 +
            l15] = (f16)acc[mi][ni][rr];
  __syncthreads();

  // epilogue: v = relu(P + A[dst] + B[src] + bM), in-place in V16
  const int rg = tid >> 4;          // 16 groups x 8 rows
  const int tn = (tid & 15) << 3;   // col 0..120
  const float4 m0v = *(const float4*)(bMl + tn);
  const float4 m1v = *(const float4*)(bMl + tn + 4);
  const float mv[8] = {m0v.x, m0v.y, m0v.z, m0v.w,
                       m1v.x, m1v.y, m1v.z, m1v.w};
#pragma unroll
  for (int i = 0; i < 8; ++i) {
    const int row = rg * 8 + i;
    const int rr = r0 + row;
    const int d = dstS[row];
    const int s = sSrc[rr];
    const f16x8 a8 = *(const f16x8*)(A + (size_t)d * HH + tn);
    const f16x8 b8 = *(const f16x8*)(B + (size_t)s * HH + tn);
    f16* vp = &V16[(size_t)row * TSTR + tn];
    const f16x8 pv = *(const f16x8*)vp;
    f16x8 o;
#pragma unroll
    for (int j = 0; j < 8; ++j)
      o[j] = (f16)fmaxf((float)pv[j] + (float)a8[j] + (float)b8[j] + mv[j],
                        0.f);
    *(f16x8*)vp = o;   // disjoint 16B segments per thread: no race
  }
  __syncthreads();

  // segmented run reduction (r4-verified): wave-uniform 32-edge strips.
  // Interior runs own ALL edges of their dst (global sort) -> plain store;
  // first/last runs of a strip -> atomicAdd. 256 thr: 2 strip passes.
  const int c = tid & 127;
  for (int sp = tid >> 7; sp < 4; sp += 2) {
    float racc = 0.f;
    int cur = dstS[sp * 32];
    bool first = true;
    for (int e2 = sp * 32; e2 < sp * 32 + 32; ++e2) {
      const int d = dstS[e2];
      if (d != cur) {
        if (first) {
          atomicAdd(&agg[(size_t)cur * HH + c], racc);
          first = false;
        } else {
          agg[(size_t)cur * HH + c] = racc;
        }
        racc = 0.f;
        cur = d;
      }
      racc += (float)V16[(size_t)e2 * TSTR + c];
    }
    atomicAdd(&agg[(size_t)cur * HH + c], racc);
  }
}

// ---------------------------------------------------------------------------
__global__ void count_kernel(const int* __restrict__ dst, int* cnt,
                             const int* __restrict__ batch, int* gcnt) {
  const int i = blockIdx.x * 256 + threadIdx.x;
  if (i < EE) atomicAdd(&cnt[dst[i]], 1);
  if (i < NN) atomicAdd(&gcnt[batch[i]], 1);
}

__global__ void scan_block(const int* __restrict__ cnt, int* excl, int* bsum,
                           int n) {
  __shared__ int s[256];
  const int tx = threadIdx.x;
  const int i = blockIdx.x * 256 + tx;
  const int v = (i < n) ? cnt[i] : 0;
  s[tx] = v;
  __syncthreads();
  for (int off = 1; off < 256; off <<= 1) {
    int tv = (tx >= off) ? s[tx - off] : 0;
    __syncthreads();
    s[tx] += tv;
    __syncthreads();
  }
  if (i < n) excl[i] = s[tx] - v;
  if (tx == 255) bsum[blockIdx.x] = s[255];
}

// parallel exclusive scan of the per-block sums (nb <= 512).
__global__ __launch_bounds__(512) void scan_bsum(int* bsum, int nb) {
  __shared__ int s[512];
  const int t = threadIdx.x;
  const int v0 = (t < nb) ? bsum[t] : 0;
  s[t] = v0;
  __syncthreads();
  for (int off = 1; off < 512; off <<= 1) {
    const int tv = (t >= off) ? s[t - off] : 0;
    __syncthreads();
    s[t] += tv;
    __syncthreads();
  }
  if (t < nb) bsum[t] = s[t] - v0;  // exclusive
}

// + fused invcnt (elementwise over the same range)
__global__ void scan_add(int* excl, const int* __restrict__ bsum,
                         const int* __restrict__ cnt, float* __restrict__ inv,
                         int n) {
  const int i = blockIdx.x * 256 + threadIdx.x;
  if (i < n) {
    excl[i] += bsum[blockIdx.x];
    inv[i] = 1.0f / (float)max(cnt[i], 1);
  }
}

__global__ void scatter_edges(const int* __restrict__ dst,
                              const int* __restrict__ src,
                              const int* __restrict__ off, int* ctr, int* sIdx,
                              int* sSrc, int* sDst, int E) {
  const int e = blockIdx.x * 256 + threadIdx.x;
  if (e >= E) return;
  const int d = dst[e];
  const int p = off[d] + atomicAdd(&ctr[d], 1);
  sIdx[p] = e;
  sSrc[p] = src[e];
  sDst[p] = d;
}

__global__ void head_kernel(const float* __restrict__ gsum,
                            const int* __restrict__ gcnt,
                            const float* __restrict__ Wh,
                            const float* __restrict__ bh,
                            float* __restrict__ out) {
  const int g = blockIdx.x;
  const int t = threadIdx.x;  // 128 threads
  float v = gsum[(size_t)g * HH + t] * Wh[t];
#pragma unroll
  for (int o = 32; o > 0; o >>= 1) v += __shfl_down(v, o, 64);
  __shared__ float red[2];
  if ((t & 63) == 0) red[t >> 6] = v;
  __syncthreads();
  if (t == 0) {
    const float s = red[0] + red[1];
    const float c = (float)max(gcnt[g], 1);
    out[g] = s / c + bh[0];
  }
}

// ---------------------------------------------------------------------------
extern "C" void kernel_launch(void* const* d_in, const int* in_sizes, int n_in,
                              void* d_out, int out_size, void* d_ws,
                              size_t ws_size, hipStream_t stream) {
  (void)in_sizes; (void)n_in; (void)out_size;
  const float* x = (const float*)d_in[0];
  const int* ei = (const int*)d_in[1];
  const float* ea = (const float*)d_in[2];
  const int* batch = (const int*)d_in[3];
  const float* Wn0 = (const float*)d_in[4];
  const float* bn0 = (const float*)d_in[5];
  const float* We0 = (const float*)d_in[6];
  const float* be0 = (const float*)d_in[7];
  const float* WM = (const float*)d_in[8];
  const float* bM = (const float*)d_in[9];
  const float* WU = (const float*)d_in[10];
  const float* bU = (const float*)d_in[11];
  const float* Wn = (const float*)d_in[12];
  const float* bn = (const float*)d_in[13];
  const float* We = (const float*)d_in[14];
  const float* be = (const float*)d_in[15];
  const float* Wh = (const float*)d_in[16];
  const float* bh = (const float*)d_in[17];

  const int* srcI = ei;       // edge_index[0]
  const int* dstI = ei + EE;  // edge_index[1]

  // workspace carve — ~141 MB (h f16)
  float* w = (float*)d_ws;
  size_t o = 0;
  f16* h16 = (f16*)(w + o);  o += (size_t)NN * HH / 2;
  float* agg = w + o;  o += (size_t)NN * HH;
  f16* A16 = (f16*)(w + o); o += (size_t)NN * HH / 2;
  f16* B16 = (f16*)(w + o); o += (size_t)NN * HH / 2;
  float* gsum = w + o; o += (size_t)GG * HH;
  float* invc = w + o; o += (size_t)NN;
  int* cnt = (int*)(w + o);  o += (size_t)NN;
  int* gcnt = (int*)(w + o); o += (size_t)GG;
  int* off = (int*)(w + o);  o += (size_t)NN;
  int* ctr = (int*)(w + o);  o += (size_t)NN;
  int* bsum = (int*)(w + o); o += 512;
  int* sIdx = (int*)(w + o); o += (size_t)EE;
  int* sSrc = (int*)(w + o); o += (size_t)EE;
  int* sDst = (int*)(w + o); o += (size_t)EE;
  f16* Wp = (f16*)(w + o);   o += (size_t)22 * HH * TSTR / 2;
  if (o * sizeof(float) > ws_size) return;  // clean diagnosable failure

  auto WB = [&](int i) { return Wp + (size_t)i * HH * TSTR; };

  const dim3 blk(256);
  const int gridN = (NN + BM - 1) / BM;   // 1563
  const int gridE = EE / 128;             // 5000 (128 edges/block)
  const int NBLK = (NN + 255) / 256;      // 391

  hipMemsetAsync(cnt, 0, (size_t)NN * sizeof(int), stream);
  hipMemsetAsync(ctr, 0, (size_t)NN * sizeof(int), stream);
  hipMemsetAsync(gsum, 0, (size_t)GG * HH * sizeof(float), stream);
  hipMemsetAsync(gcnt, 0, (size_t)GG * sizeof(int), stream);

  count_kernel<<<(EE + 255) / 256, blk, 0, stream>>>(dstI, cnt, batch, gcnt);
  scan_block<<<NBLK, blk, 0, stream>>>(cnt, off, bsum, NN);
  scan_bsum<<<1, dim3(512), 0, stream>>>(bsum, NBLK);
  scan_add<<<NBLK, blk, 0, stream>>>(off, bsum, cnt, invc, NN);
  scatter_edges<<<(EE + 255) / 256, blk, 0, stream>>>(dstI, srcI, off, ctr,
                                                      sIdx, sSrc, sDst, EE);
  prep_w<<<22 * 8, blk, 0, stream>>>(We0, We, WM, Wn0, Wn, WU, Wp);

  // encoder + A/B(0): h = relu(x@Wn0+bn0); A=h@WM1(0); B=h@WM2(0)
  fused_enc<<<gridN, blk, 0, stream>>>(x, WB(6), bn0, h16, WB(7), WB(10),
                                       A16, B16, NN);

  for (int l = 0; l < LL; ++l) {
    hipMemsetAsync(agg, 0, (size_t)NN * HH * sizeof(float), stream);
    switch (l) {
      case 0:
        msg_k<0><<<gridE, blk, 0, stream>>>(ea, WB(0), be0, WB(1), be, WB(3),
                                            bM + 0 * HH, A16, B16, sIdx, sSrc,
                                            sDst, agg);
        break;
      case 1:
        msg_k<1><<<gridE, blk, 0, stream>>>(ea, WB(0), be0, WB(1), be, WB(4),
                                            bM + 1 * HH, A16, B16, sIdx, sSrc,
                                            sDst, agg);
        break;
      default:
        msg_k<2><<<gridE, blk, 0, stream>>>(ea, WB(0), be0, WB(1), be, WB(5),
                                            bM + 2 * HH, A16, B16, sIdx, sSrc,
                                            sDst, agg);
        break;
    }
    // fused: h' = relu([h,agg/cnt]@WU+bU); h'' = relu(h'@Wn+bn);
    //        l<2: A/B(l+1) projections; l==2: pool h'' into gsum
    if (l < LL - 1) {
      fused_upd<1><<<gridN, blk, 0, stream>>>(
          h16, WB(16 + 2 * l), bU + l * HH, agg, invc, WB(13 + l), bn + l * HH,
          WB(7 + l + 1), WB(10 + l + 1), h16, A16, B16, nullptr, nullptr, NN);
    } else {
      fused_upd<0><<<gridN, blk, 0, stream>>>(
          h16, WB(16 + 2 * l), bU + l * HH, agg, invc, WB(13 + l), bn + l * HH,
          nullptr, nullptr, nullptr, nullptr, nullptr, batch, gsum, NN);
    }
  }

  head_kernel<<<GG, dim3(128), 0, stream>>>(gsum, gcnt, Wh, bh, (float*)d_out);
}